// Round 2
// baseline (5475.290 us; speedup 1.0000x reference)
//
#include <hip/hip_runtime.h>

// Equivariant graph attention — fp32. R2 restructure:
//  - k_edges: FLAT edge kernel (CSR order): k-MLP (8 edges/wave, layer-1 in
//    VGPRs, layer-2 in LDS) -> logits vs A[dst] (global, L1-hot via CSR
//    locality) -> expw store. No barriers in main loop.
//  - k_nodes: one wave per node: z from expw, v-MLP 8-edges-dense, in-register
//    channel aggregation, fused output linear. No wv materialization.

constexpr float INV3    = 0.57735026918962576f;  // 1/sqrt(3)
constexpr float INV_SQ8 = 0.35355339059327373f;  // 1/sqrt(8)   (folded into w1 regs)
constexpr float INV_HID = 0.125f;                // 1/sqrt(64)  (folded into LDS w2)
constexpr float INV_FAN = 0.015625f;             // 1/sqrt(4*32*32)
constexpr float INV_L   = 0.125f;                // 1/sqrt(64)

__device__ __forceinline__ float gelu_tanh(float x) {
  float u = 0.7978845608028654f * (x + 0.044715f * x * x * x);
  float e = __expf(2.0f * u);
  return x * (1.0f - 1.0f / (e + 1.0f));
}

// ---------------- CSR build ----------------
__global__ void k_zero(int* __restrict__ p, int n) {
  int i = blockIdx.x * 256 + threadIdx.x;
  if (i < n) p[i] = 0;
}

__global__ void k_hist(const int* __restrict__ dst, int* __restrict__ cnt, int E) {
  int e = blockIdx.x * 256 + threadIdx.x;
  if (e < E) atomicAdd(&cnt[dst[e]], 1);
}

// single-block exclusive scan, 4 elements/thread (1024/chunk)
__global__ __launch_bounds__(256) void k_scan(const int* __restrict__ cnt,
                                              int* __restrict__ rowptr, int N) {
  __shared__ int wsum[4];
  __shared__ int woff[4];
  __shared__ int carry;
  int t = threadIdx.x, wave = t >> 6, lane = t & 63;
  if (t == 0) { carry = 0; rowptr[0] = 0; }
  __syncthreads();
  for (int base = 0; base < N; base += 1024) {
    int i0 = base + t * 4;
    int c0 = (i0     < N) ? cnt[i0]     : 0;
    int c1 = (i0 + 1 < N) ? cnt[i0 + 1] : 0;
    int c2 = (i0 + 2 < N) ? cnt[i0 + 2] : 0;
    int c3 = (i0 + 3 < N) ? cnt[i0 + 3] : 0;
    int s0 = c0, s1 = s0 + c1, s2 = s1 + c2, s3 = s2 + c3;
    int inc = s3;
#pragma unroll
    for (int off = 1; off < 64; off <<= 1) {
      int y = __shfl_up(inc, off, 64);
      if (lane >= off) inc += y;
    }
    if (lane == 63) wsum[wave] = inc;
    __syncthreads();
    if (t == 0) {
      int r = 0;
      for (int w = 0; w < 4; w++) { woff[w] = r; r += wsum[w]; }
    }
    __syncthreads();
    int excl = inc - s3 + woff[wave] + carry;
    if (i0     < N) rowptr[i0 + 1] = excl + s0;
    if (i0 + 1 < N) rowptr[i0 + 2] = excl + s1;
    if (i0 + 2 < N) rowptr[i0 + 3] = excl + s2;
    if (i0 + 3 < N) rowptr[i0 + 4] = excl + s3;
    __syncthreads();
    if (t == 255) carry = excl + s3;
    __syncthreads();
  }
}

__global__ void k_fill(const int* __restrict__ dst, const int* __restrict__ rowptr,
                       int* __restrict__ cursor, int* __restrict__ csr, int E) {
  int e = blockIdx.x * 256 + threadIdx.x;
  if (e < E) {
    int d = dst[e];
    int s = atomicAdd(&cursor[d], 1);
    csr[rowptr[d] + s] = e;
  }
}

// ---------------- per-node A precompute ----------------
// A layout per node (1024 f32): A0[4][32] | A1[4][32] | A2[4][32][3] | A3[4][32][3]
__global__ __launch_bounds__(256) void k_nodeA(const float* __restrict__ node_f,
                                               const float* __restrict__ Wdot,
                                               float* __restrict__ A, int N) {
  __shared__ float Wd[16384];
  __shared__ float nfs[32 * 128];
  int t = threadIdx.x;
  for (int i = t; i < 16384; i += 256) Wd[i] = Wdot[i];
  int n0 = blockIdx.x * 32;
  int nEnd = min(32, N - n0);
  for (int i = t; i < nEnd * 128; i += 256) nfs[i] = node_f[n0 * 128 + i];
  __syncthreads();
  for (int nn = 0; nn < nEnd; ++nn) {
    const float* nf = &nfs[nn * 128];
    float* An = &A[(size_t)(n0 + nn) * 1024];
#pragma unroll
    for (int k = 0; k < 4; k++) {
      int o = t + k * 256;
      float acc = 0.f;
      if (o < 256) {
        int term = o >> 7, h = (o >> 5) & 3, v = o & 31;
        const float* W = &Wd[term * 4096 + h * 1024 + v];
#pragma unroll
        for (int u = 0; u < 32; u++) acc += W[u * 32] * nf[u];
      } else {
        int r = o - 256;
        int term = 2 + r / 384;
        int rr = r % 384;
        int h = rr / 96, q = rr % 96, v = q / 3, d = q - 3 * (q / 3);
        const float* W = &Wd[term * 4096 + h * 1024 + v];
#pragma unroll
        for (int u = 0; u < 32; u++) acc += W[u * 32] * nf[32 + u * 3 + d];
      }
      An[o] = acc;
    }
  }
}

// ---------------- flat edge pass: k-MLP + logits -> expw ----------------
__global__ __launch_bounds__(256, 2) void k_edges(
    const int* __restrict__ csr, const int* __restrict__ esrc,
    const int* __restrict__ edst,
    const float* __restrict__ xattr,   // E x 8
    const float* __restrict__ eattr,   // E x 4
    const float* __restrict__ cutoff,  // E
    const float* __restrict__ node_f,  // N x 128
    const float* __restrict__ wk1, const float* __restrict__ bk1,
    const float* __restrict__ wk2,
    const float* __restrict__ A,       // N x 1024
    float* __restrict__ expwb,         // E x 4, CSR slot order
    int E)
{
  __shared__ float4 wqk[16 * 128];   // 32 KiB: [l/4][j] . [l%4], pre-scaled INV_HID
  __shared__ float  hs[4][8][64];    // 8 KiB, wave-local

  int t = threadIdx.x, wave = t >> 6, lane = t & 63;
  for (int idx = t; idx < 8192; idx += 256) {
    int l = idx >> 7, j = idx & 127;
    ((float*)&wqk[(l >> 2) * 128 + j])[l & 3] = wk2[idx] * INV_HID;
  }
  // layer-1 weights in registers (INV_SQ8 folded)
  float w1r[8];
#pragma unroll
  for (int r = 0; r < 8; r++) w1r[r] = wk1[r * 64 + lane] * INV_SQ8;
  float b1r = bk1[lane];
  __syncthreads();

  int v = lane & 31;
  bool hi = lane >= 32;
  const float4* xattr4 = (const float4*)xattr;
  const float4* eattr4 = (const float4*)eattr;

  for (int it = 0; it < 8; ++it) {
    int i0w = blockIdx.x * 256 + it * 32 + wave * 8;
    int eid[8];
#pragma unroll
    for (int k = 0; k < 8; k++) {
      int i = i0w + k;
      eid[k] = (i < E) ? csr[i] : 0;
    }
    // layer 1 (all loads broadcast; 8 independent edges pipeline)
#pragma unroll
    for (int k = 0; k < 8; k++) {
      float4 xa = xattr4[(size_t)eid[k] * 2];
      float4 xb = xattr4[(size_t)eid[k] * 2 + 1];
      float acc = xa.x * w1r[0] + xa.y * w1r[1] + xa.z * w1r[2] + xa.w * w1r[3]
                + xb.x * w1r[4] + xb.y * w1r[5] + xb.z * w1r[6] + xb.w * w1r[7];
      hs[wave][k][lane] = gelu_tanh(acc + b1r);
    }
    // layer 2: lane owns outputs j=lane, j=lane+64 for 8 edges
    float a0[8] = {0, 0, 0, 0, 0, 0, 0, 0}, a1[8] = {0, 0, 0, 0, 0, 0, 0, 0};
#pragma unroll
    for (int q = 0; q < 16; ++q) {
      float4 wA = wqk[q * 128 + lane];
      float4 wB = wqk[q * 128 + 64 + lane];
#pragma unroll
      for (int k = 0; k < 8; k++) {
        float4 hq = *(const float4*)&hs[wave][k][q * 4];
        a0[k] += hq.x * wA.x + hq.y * wA.y + hq.z * wA.z + hq.w * wA.w;
        a1[k] += hq.x * wB.x + hq.y * wB.y + hq.z * wB.z + hq.w * wB.w;
      }
    }
    // logits epilogue
    float pw = 0.f, cw = 0.f;
#pragma unroll
    for (int k = 0; k < 8; k++) {
      if (i0w + k >= E) continue;  // wave-uniform
      int e = eid[k];
      const float* Arow = A + (size_t)edst[e] * 1024;
      const float* nf = node_f + (size_t)esrc[e] * 128;
      float4 ya = eattr4[e];
      float cutv = cutoff[e];
      float nf0 = nf[hi ? 32 + 3 * v : v];
      float nf1 = nf[hi ? 33 + 3 * v : v];
      float nf2 = nf[hi ? 34 + 3 * v : v];
      // lo: k0 = w0*sxs*ys          kv0 term: INV3*w2*sxs * (A2[h,v,:].yv)
      // hi: k1 = w0*(sxv.yv)*INV3   kv1 term: INV3*w2*ys  * (A3[h,v,:].sxv)
      float w0 = a0[k], w2 = a1[k];
      float dotv = nf0 * ya.y + nf1 * ya.z + nf2 * ya.w;
      float kscal = hi ? (w0 * dotv * INV3) : (w0 * nf0 * ya.x);
      float cf = INV3 * w2 * (hi ? ya.x : nf0);
      float m0 = hi ? nf0 : ya.y, m1 = hi ? nf1 : ya.z, m2 = hi ? nf2 : ya.w;
      int off01 = hi ? 128 : 0;
      int off23 = 256 + (hi ? 384 : 0);
      float p0, p1, p2, p3;
      {
        const float* Ap = Arow + off23 + v * 3;
        float ta = Arow[off01 + v];
        p0 = ta * kscal + cf * (Ap[0] * m0 + Ap[1] * m1 + Ap[2] * m2);
        ta = Arow[off01 + 32 + v];  Ap += 96;
        p1 = ta * kscal + cf * (Ap[0] * m0 + Ap[1] * m1 + Ap[2] * m2);
        ta = Arow[off01 + 64 + v];  Ap += 96;
        p2 = ta * kscal + cf * (Ap[0] * m0 + Ap[1] * m1 + Ap[2] * m2);
        ta = Arow[off01 + 96 + v];  Ap += 96;
        p3 = ta * kscal + cf * (Ap[0] * m0 + Ap[1] * m1 + Ap[2] * m2);
      }
#pragma unroll
      for (int off = 32; off; off >>= 1) {
        p0 += __shfl_xor(p0, off, 64);
        p1 += __shfl_xor(p1, off, 64);
        p2 += __shfl_xor(p2, off, 64);
        p3 += __shfl_xor(p3, off, 64);
      }
      float psel = (lane & 2) ? ((lane & 1) ? p3 : p2) : ((lane & 1) ? p1 : p0);
      if ((lane >> 2) == k) { pw = psel; cw = cutv; }
    }
    if (lane < 32) {
      int iw = i0w + (lane >> 2);
      if (iw < E) expwb[(size_t)i0w * 4 + lane] = cw * __expf(pw * INV_FAN);
    }
  }
}

// ---------------- per-node pass: z, v-MLP (8-edge dense), agg, linear ----------------
__global__ __launch_bounds__(256, 2) void k_nodes(
    const int* __restrict__ csr, const int* __restrict__ rowptr,
    const int* __restrict__ esrc,
    const float* __restrict__ xattr, const float* __restrict__ eattr,
    const float* __restrict__ node_f,
    const float* __restrict__ wv1, const float* __restrict__ bv1,
    const float* __restrict__ wv2,
    const float* __restrict__ Wls, const float* __restrict__ Wlv,
    const float* __restrict__ expwb,
    float* __restrict__ out, int N)
{
  __shared__ float4 wqv[16 * 128];   // 32 KiB
  __shared__ float  hs[4][8][64];    // 8 KiB, wave-local
  __shared__ float  wls[2048];       // 8 KiB
  __shared__ float  wlv[2048];       // 8 KiB
  __shared__ float  aggN[4][256];    // 4 KiB, wave-local

  int t = threadIdx.x, wave = t >> 6, lane = t & 63;
  for (int idx = t; idx < 8192; idx += 256) {
    int l = idx >> 7, j = idx & 127;
    ((float*)&wqv[(l >> 2) * 128 + j])[l & 3] = wv2[idx] * INV_HID;
  }
  for (int i = t; i < 2048; i += 256) { wls[i] = Wls[i]; wlv[i] = Wlv[i]; }
  float w1r[8];
#pragma unroll
  for (int r = 0; r < 8; r++) w1r[r] = wv1[r * 64 + lane] * INV_SQ8;
  float b1r = bv1[lane];
  __syncthreads();   // the only barrier

  int n = blockIdx.x * 4 + wave;
  if (n >= N) return;

  int v = lane & 31;
  bool hi = lane >= 32;
  int hh = v >> 3;
  const float4* xattr4 = (const float4*)xattr;
  const float4* eattr4 = (const float4*)eattr;

  int row0 = rowptr[n];
  int deg = rowptr[n + 1] - row0;

  // z per head, then rz for this lane's head
  float pz = 0.f;
  {
    int hz = lane & 3;
    for (int s = lane >> 2; s < deg; s += 16) pz += expwb[(size_t)(row0 + s) * 4 + hz];
#pragma unroll
    for (int off = 4; off < 64; off <<= 1) pz += __shfl_xor(pz, off, 64);
  }
  float zf = __shfl(pz, hh, 64);
  zf = (zf == 0.f) ? 1.f : zf;
  float rz = 1.f / zf;

  float accS = 0.f, acc0 = 0.f, acc1 = 0.f, acc2 = 0.f;
  int iters = (deg + 7) >> 3;
  for (int it = 0; it < iters; ++it) {
    int sb = it * 8;
    int eid[8];
#pragma unroll
    for (int k = 0; k < 8; k++) {
      int s = sb + k;
      eid[k] = csr[row0 + (s < deg ? s : 0)];
    }
#pragma unroll
    for (int k = 0; k < 8; k++) {
      float4 xa = xattr4[(size_t)eid[k] * 2];
      float4 xb = xattr4[(size_t)eid[k] * 2 + 1];
      float acc = xa.x * w1r[0] + xa.y * w1r[1] + xa.z * w1r[2] + xa.w * w1r[3]
                + xb.x * w1r[4] + xb.y * w1r[5] + xb.z * w1r[6] + xb.w * w1r[7];
      hs[wave][k][lane] = gelu_tanh(acc + b1r);
    }
    float a0[8] = {0, 0, 0, 0, 0, 0, 0, 0}, a1[8] = {0, 0, 0, 0, 0, 0, 0, 0};
#pragma unroll
    for (int q = 0; q < 16; ++q) {
      float4 wA = wqv[q * 128 + lane];
      float4 wB = wqv[q * 128 + 64 + lane];
#pragma unroll
      for (int k = 0; k < 8; k++) {
        float4 hq = *(const float4*)&hs[wave][k][q * 4];
        a0[k] += hq.x * wA.x + hq.y * wA.y + hq.z * wA.z + hq.w * wA.w;
        a1[k] += hq.x * wB.x + hq.y * wB.y + hq.z * wB.z + hq.w * wB.w;
      }
    }
#pragma unroll
    for (int k = 0; k < 8; k++) {
      int s = sb + k;
      if (s < deg) {   // wave-uniform
        size_t i = (size_t)(row0 + s);
        int e = eid[k];
        float4 ya = eattr4[e];
        const float* nf = node_f + (size_t)esrc[e] * 128;
        float nf0 = nf[hi ? 32 + 3 * v : v];
        float nf1 = nf[hi ? 33 + 3 * v : v];
        float nf2 = nf[hi ? 34 + 3 * v : v];
        float ew = expwb[i * 4 + hh];
        float sa = sqrtf(fmaxf(ew * rz, 0.f));
        float dotv = nf0 * ya.y + nf1 * ya.z + nf2 * ya.w;
        float sterm = hi ? dotv * INV3 : nf0 * ya.x;
        accS += a0[k] * sterm * sa;
        float coef = a1[k] * sa * (hi ? ya.x : nf0);
        float m0 = hi ? nf0 : ya.y, m1 = hi ? nf1 : ya.z, m2 = hi ? nf2 : ya.w;
        acc0 += coef * m0; acc1 += coef * m1; acc2 += coef * m2;
      }
    }
  }
  // wave-local channel staging (each lane owns 4 exclusive channels)
  {
    int chS = hi ? 32 + v : v;
    int chV = (hi ? 160 : 64) + 3 * v;
    aggN[wave][chS] = accS;
    aggN[wave][chV] = acc0; aggN[wave][chV + 1] = acc1; aggN[wave][chV + 2] = acc2;
  }
  const float* agg = aggN[wave];
  // output linear: lane computes outputs 2*lane, 2*lane+1
#pragma unroll
  for (int jj = 0; jj < 2; ++jj) {
    int j = 2 * lane + jj;
    float o = 0.f;
    if (j < 32) {
#pragma unroll
      for (int u = 0; u < 64; u++) o += agg[u] * wls[u * 32 + j];
    } else {
      int i2 = j - 32, w2 = i2 / 3, d2 = i2 - 3 * w2;
#pragma unroll
      for (int u = 0; u < 64; u++) o += agg[64 + u * 3 + d2] * wlv[u * 32 + w2];
    }
    out[(size_t)n * 128 + j] = o * INV_L;
  }
}

// ---------------- host launcher ----------------
extern "C" void kernel_launch(void* const* d_in, const int* in_sizes, int n_in,
                              void* d_out, int out_size, void* d_ws, size_t ws_size,
                              hipStream_t stream) {
  const int*   esrc   = (const int*)d_in[0];
  const int*   edst   = (const int*)d_in[1];
  const float* xattr  = (const float*)d_in[2];
  const float* eattr  = (const float*)d_in[3];
  const float* cutoff = (const float*)d_in[4];
  const float* node_f = (const float*)d_in[5];
  const float* wk1    = (const float*)d_in[6];
  const float* bk1    = (const float*)d_in[7];
  const float* wk2    = (const float*)d_in[8];
  const float* wv1    = (const float*)d_in[9];
  const float* bv1    = (const float*)d_in[10];
  const float* wv2    = (const float*)d_in[11];
  const float* Wdot   = (const float*)d_in[12];
  const float* Wls    = (const float*)d_in[13];
  const float* Wlv    = (const float*)d_in[14];
  float* out = (float*)d_out;

  int E = in_sizes[0];
  int N = in_sizes[5] / 128;

  // workspace layout (~47.6 MB)
  float* A     = (float*)d_ws;                 // N*1024
  float* expwb = A + (size_t)N * 1024;         // E*4
  int* counts  = (int*)(expwb + (size_t)E * 4);
  int* cursor  = counts + N;
  int* rowptr  = cursor + N;
  int* csr     = rowptr + (N + 1);

  k_zero<<<(2 * N + 255) / 256, 256, 0, stream>>>(counts, 2 * N);
  k_hist<<<(E + 255) / 256, 256, 0, stream>>>(edst, counts, E);
  k_scan<<<1, 256, 0, stream>>>(counts, rowptr, N);
  k_fill<<<(E + 255) / 256, 256, 0, stream>>>(edst, rowptr, cursor, csr, E);
  k_nodeA<<<(N + 31) / 32, 256, 0, stream>>>(node_f, Wdot, A, N);
  k_edges<<<(E + 255) / 256, 256, 0, stream>>>(csr, esrc, edst, xattr, eattr, cutoff,
                                               node_f, wk1, bk1, wk2, A, expwb, E);
  k_nodes<<<(N + 3) / 4, 256, 0, stream>>>(csr, rowptr, esrc, xattr, eattr, node_f,
                                           wv1, bv1, wv2, Wls, Wlv, expwb, out, N);
}